// Round 1
// baseline (847.945 us; speedup 1.0000x reference)
//
#include <hip/hip_runtime.h>
#include <math.h>

#define BDIM 512
#define T_STEPS 20

__device__ __forceinline__ float sigm(float v) { return 1.0f / (1.0f + expf(-v)); }
__device__ __forceinline__ float dot4(float4 a, float4 w, float acc) {
  acc = fmaf(a.x, w.x, acc);
  acc = fmaf(a.y, w.y, acc);
  acc = fmaf(a.z, w.z, acc);
  acc = fmaf(a.w, w.w, acc);
  return acc;
}

// One block per batch b (grid=128). 512 threads: node i = tid>>3 (64 nodes),
// sub-lane s = tid&7. A node's 8 lanes always live in ONE wave (8 rows/wave),
// so all row-local LDS producer->consumer pairs need no barrier.
__global__ __launch_bounds__(BDIM, 2)
void traj_disc(const float* __restrict__ x, const float* __restrict__ dmat,
               const float* __restrict__ bmat, const float* __restrict__ hmat,
               const float* __restrict__ maskp,
               const float* __restrict__ embW, const float* __restrict__ embb,
               const float* __restrict__ Wih, const float* __restrict__ Whh,
               const float* __restrict__ bih, const float* __restrict__ bhh,
               const float* __restrict__ dom,
               const float* __restrict__ e2aW, const float* __restrict__ e2ab,
               const float* __restrict__ spaW, const float* __restrict__ spab,
               const float* __restrict__ a2eW, const float* __restrict__ a2eb,
               const float* __restrict__ clsW, const float* __restrict__ clsb,
               const float* __restrict__ h0, const float* __restrict__ c0,
               float* __restrict__ out)
{
  // Packed LSTM gate rows: [0:16) W_ih, [16:48) W_hh, [48] b_ih+b_hh, pitch 52.
  // Pitches 52/36/68 are odd multiples of 4: float4 rows stay 16B-aligned AND
  // the 8 distinct rows hit 8 distinct bank groups (52*s mod 32 = 20s: distinct).
  __shared__ __align__(16) float sg[128*52];
  __shared__ float sdom[144];
  __shared__ __align__(16) float se2a[32*36];
  __shared__ float se2ab[32];
  __shared__ __align__(16) float sspa[32*68];
  __shared__ float sspab[32];
  __shared__ __align__(16) float sa2e[32*36];
  __shared__ float sa2eb[32];
  __shared__ float sembW[32];
  __shared__ float sembb[16];
  __shared__ float sclsW[32];
  __shared__ float sclsb;
  __shared__ __align__(16) float sh[64*36];   // hidden state rows, pitch 36
  __shared__ __align__(16) float sa[64*36];   // attention-space a (reused for z)
  __shared__ float smk[64];

  const int tid = threadIdx.x;
  const int b = blockIdx.x;
  const int i = tid >> 3;   // node 0..63
  const int s = tid & 7;    // sub-lane 0..7

  // ---- one-time staging ----
  for (int idx = tid; idx < 2048; idx += BDIM) sg[(idx >> 4)*52 + (idx & 15)] = Wih[idx];
  for (int idx = tid; idx < 4096; idx += BDIM) sg[(idx >> 5)*52 + 16 + (idx & 31)] = Whh[idx];
  if (tid < 128) sg[tid*52 + 48] = bih[tid] + bhh[tid];
  if (tid < 144) sdom[tid] = dom[tid];
  for (int idx = tid; idx < 1024; idx += BDIM) se2a[(idx >> 5)*36 + (idx & 31)] = e2aW[idx];
  for (int idx = tid; idx < 2048; idx += BDIM) sspa[(idx >> 6)*68 + (idx & 63)] = spaW[idx];
  for (int idx = tid; idx < 1024; idx += BDIM) sa2e[(idx >> 5)*36 + (idx & 31)] = a2eW[idx];
  if (tid < 32) { se2ab[tid] = e2ab[tid]; sspab[tid] = spab[tid]; sa2eb[tid] = a2eb[tid];
                  sembW[tid] = embW[tid]; sclsW[tid] = clsW[tid]; }
  if (tid < 16) sembb[tid] = embb[tid];
  if (tid == 0) sclsb = clsb[0];
  for (int idx = tid; idx < 2048; idx += BDIM) sh[(idx >> 5)*36 + (idx & 31)] = h0[(size_t)b*2048 + idx];
  float cst[4];  // cell state: this thread owns c[i][s+8u]
  #pragma unroll
  for (int u = 0; u < 4; ++u) cst[u] = c0[(size_t)b*2048 + i*32 + s + 8*u];
  __syncthreads();

  const size_t nb = (size_t)b*64 + i;

  for (int t = 0; t < T_STEPS; ++t) {
    if (tid < 64) smk[tid] = maskp[((size_t)b*64 + tid)*20 + t];
    __syncthreads();  // B1: smk visible

    // ---- P1: LSTM cell (gate order i,f,g,o); each lane does hh = s+8u ----
    {
      float x0 = x[(nb*20 + t)*2 + 0];
      float x1 = x[(nb*20 + t)*2 + 1];
      float xv[16];
      #pragma unroll
      for (int e = 0; e < 16; ++e)
        xv[e] = fmaf(x0, sembW[2*e], fmaf(x1, sembW[2*e+1], sembb[e]));
      const float4* hrow = (const float4*)(sh + i*36);
      float4 hv[8];
      #pragma unroll
      for (int h4 = 0; h4 < 8; ++h4) hv[h4] = hrow[h4];
      float hl[4];
      #pragma unroll
      for (int u = 0; u < 4; ++u) {
        const int hh = s + 8*u;
        float acc[4];
        #pragma unroll
        for (int q = 0; q < 4; ++q) {
          const float* row = sg + (q*32 + hh)*52;
          float a0 = row[48];
          const float4* wi = (const float4*)row;
          #pragma unroll
          for (int e4 = 0; e4 < 4; ++e4) {
            float4 w = wi[e4];
            a0 = fmaf(xv[4*e4+0], w.x, a0);
            a0 = fmaf(xv[4*e4+1], w.y, a0);
            a0 = fmaf(xv[4*e4+2], w.z, a0);
            a0 = fmaf(xv[4*e4+3], w.w, a0);
          }
          const float4* wh = (const float4*)(row + 16);
          #pragma unroll
          for (int h4 = 0; h4 < 8; ++h4) a0 = dot4(hv[h4], wh[h4], a0);
          acc[q] = a0;
        }
        float ig = sigm(acc[0]);
        float fg = sigm(acc[1]);
        float gg = tanhf(acc[2]);
        float og = sigm(acc[3]);
        cst[u] = fmaf(fg, cst[u], ig*gg);
        hl[u] = og * tanhf(cst[u]);
      }
      // same-wave: all hv reads above precede these writes in program order
      #pragma unroll
      for (int u = 0; u < 4; ++u) sh[i*36 + s + 8*u] = hl[u];
    }

    // ---- P2: a = h @ enc2att_W^T + b (row i owned by this wave) ----
    {
      const float4* hrow = (const float4*)(sh + i*36);
      float4 hv[8];
      #pragma unroll
      for (int h4 = 0; h4 < 8; ++h4) hv[h4] = hrow[h4];
      #pragma unroll
      for (int u = 0; u < 4; ++u) {
        const int k = s + 8*u;
        float acc = se2ab[k];
        const float4* wr = (const float4*)(se2a + k*36);
        #pragma unroll
        for (int h4 = 0; h4 < 8; ++h4) acc = dot4(hv[h4], wr[h4], acc);
        sa[i*36 + k] = acc;
      }
    }
    __syncthreads();  // B2: sa visible to cross-row readers

    // ---- P3+P4: spatial attention + spa matmul on per-lane partials ----
    float zv[4];
    {
      const size_t ebase = (nb*20 + t)*64;
      const float mi = smk[i];
      float att[32];
      #pragma unroll
      for (int m = 0; m < 32; ++m) att[m] = 0.0f;
      float rs = 0.0f;
      const float4* sa4 = (const float4*)sa;
      #pragma unroll
      for (int jj = 0; jj < 8; ++jj) {
        const int j = s + 8*jj;   // adjacent lanes -> adjacent j: coalesced
        float dm = dmat[ebase + j];
        float bm = bmat[ebase + j];
        float hm = hmat[ebase + j];
        int ib = (int)floorf(bm / 30.0f); ib = ib < 0 ? 0 : (ib > 11 ? 11 : ib);
        int ih = (int)floorf(hm / 30.0f); ih = ih < 0 ? 0 : (ih > 11 ? 11 : ih);
        float wv = fmaxf(sdom[ib*12 + ih] - dm, 0.0f) * (mi * smk[j]);
        wv = (j == i) ? 0.0f : wv;
        rs += wv;
        #pragma unroll
        for (int m4 = 0; m4 < 8; ++m4) {
          float4 av = sa4[j*9 + m4];   // pitch 36 floats = 9 float4
          att[4*m4+0] = fmaf(wv, av.x, att[4*m4+0]);
          att[4*m4+1] = fmaf(wv, av.y, att[4*m4+1]);
          att[4*m4+2] = fmaf(wv, av.z, att[4*m4+2]);
          att[4*m4+3] = fmaf(wv, av.w, att[4*m4+3]);
        }
      }
      rs += __shfl_xor(rs, 1);
      rs += __shfl_xor(rs, 2);
      rs += __shfl_xor(rs, 4);
      const float inv = 1.0f / (rs + 1e-12f);
      // att-half of spa matmul on UNREDUCED partials (linear in att), then
      // reduce only the 4 per-lane z-partials: 12 shuffles instead of a
      // 32-wide LDS round-trip.
      float zatt[4];
      #pragma unroll
      for (int u = 0; u < 4; ++u) {
        const int k = s + 8*u;
        float acc = 0.0f;
        const float4* wr = (const float4*)(sspa + k*68 + 32);
        #pragma unroll
        for (int m4 = 0; m4 < 8; ++m4) {
          float4 w = wr[m4];
          acc = fmaf(att[4*m4+0], w.x, acc);
          acc = fmaf(att[4*m4+1], w.y, acc);
          acc = fmaf(att[4*m4+2], w.z, acc);
          acc = fmaf(att[4*m4+3], w.w, acc);
        }
        zatt[u] = acc;
      }
      #pragma unroll
      for (int u = 0; u < 4; ++u) {
        zatt[u] += __shfl_xor(zatt[u], 1);
        zatt[u] += __shfl_xor(zatt[u], 2);
        zatt[u] += __shfl_xor(zatt[u], 4);
      }
      const float4* arow = (const float4*)(sa + i*36);
      float4 av[8];
      #pragma unroll
      for (int m4 = 0; m4 < 8; ++m4) av[m4] = arow[m4];
      #pragma unroll
      for (int u = 0; u < 4; ++u) {
        const int k = s + 8*u;
        float acc = sspab[k];
        const float4* wr = (const float4*)(sspa + k*68);
        #pragma unroll
        for (int m4 = 0; m4 < 8; ++m4) acc = dot4(av[m4], wr[m4], acc);
        zv[u] = tanhf(acc + zatt[u]*inv);
      }
    }
    __syncthreads();  // B3: all cross-row sa reads done -> reuse sa for z
    #pragma unroll
    for (int u = 0; u < 4; ++u) sa[i*36 + s + 8*u] = zv[u];

    // ---- P5: h = z @ att2enc_W^T + b (row-local, no barrier) ----
    {
      const float4* zrow = (const float4*)(sa + i*36);
      float4 zr[8];
      #pragma unroll
      for (int m4 = 0; m4 < 8; ++m4) zr[m4] = zrow[m4];
      #pragma unroll
      for (int u = 0; u < 4; ++u) {
        const int hh = s + 8*u;
        float acc = sa2eb[hh];
        const float4* wr = (const float4*)(sa2e + hh*36);
        #pragma unroll
        for (int m4 = 0; m4 < 8; ++m4) acc = dot4(zr[m4], wr[m4], acc);
        sh[i*36 + hh] = acc;
      }
    }
    // next iteration: B1 orders smk rewrite; sh/sa row-local accesses are
    // same-wave; B2 orders the new sa publish before cross-row reads.
  }
  __syncthreads();

  // ---- classifier head ----
  if (tid < 64) {
    float acc = sclsb;
    #pragma unroll
    for (int hh = 0; hh < 32; ++hh) acc = fmaf(sh[tid*36 + hh], sclsW[hh], acc);
    out[(size_t)b*64 + tid] = sigm(tanhf(acc));
  }
}

extern "C" void kernel_launch(void* const* d_in, const int* in_sizes, int n_in,
                              void* d_out, int out_size, void* d_ws, size_t ws_size,
                              hipStream_t stream) {
  (void)in_sizes; (void)n_in; (void)d_ws; (void)ws_size; (void)out_size;
  const float* x    = (const float*)d_in[0];
  const float* dmat = (const float*)d_in[1];
  const float* bmat = (const float*)d_in[2];
  const float* hmat = (const float*)d_in[3];
  const float* mask = (const float*)d_in[4];
  const float* embW = (const float*)d_in[5];
  const float* embb = (const float*)d_in[6];
  const float* Wih  = (const float*)d_in[7];
  const float* Whh  = (const float*)d_in[8];
  const float* bih  = (const float*)d_in[9];
  const float* bhh  = (const float*)d_in[10];
  const float* dom  = (const float*)d_in[11];
  const float* e2aW = (const float*)d_in[12];
  const float* e2ab = (const float*)d_in[13];
  const float* spaW = (const float*)d_in[14];
  const float* spab = (const float*)d_in[15];
  const float* a2eW = (const float*)d_in[16];
  const float* a2eb = (const float*)d_in[17];
  const float* clsW = (const float*)d_in[18];
  const float* clsb = (const float*)d_in[19];
  const float* h0   = (const float*)d_in[20];
  const float* c0   = (const float*)d_in[21];
  float* out = (float*)d_out;

  traj_disc<<<dim3(128), dim3(BDIM), 0, stream>>>(
      x, dmat, bmat, hmat, mask, embW, embb, Wih, Whh, bih, bhh, dom,
      e2aW, e2ab, spaW, spab, a2eW, a2eb, clsW, clsb, h0, c0, out);
}